// Round 7
// baseline (495.000 us; speedup 1.0000x reference)
//
#include <hip/hip_runtime.h>
#include <math.h>

#define BB 4
#define SS 4096
#define EE 512
#define HH 64
#define NSPLIT 8
#define NQ (BB * SS)          // 16384 rows

typedef _Float16 f16x8 __attribute__((ext_vector_type(8)));
typedef short    s16x8 __attribute__((ext_vector_type(8)));
typedef float    f32x4 __attribute__((ext_vector_type(4)));

static __device__ __forceinline__ unsigned short f2h(float f) {
    _Float16 h = (_Float16)f;
    return __builtin_bit_cast(unsigned short, h);
}

static __device__ __forceinline__ f32x4 mfma_f16(s16x8 a, s16x8 b, f32x4 c) {
    return __builtin_amdgcn_mfma_f32_16x16x32_f16(
        __builtin_bit_cast(f16x8, a), __builtin_bit_cast(f16x8, b), c, 0, 0, 0);
}

// ---------------------------------------------------------------------------
// W prep: fp32 W[512][64] -> transposed fp16 WT [mat][n=64][k=512].
// ---------------------------------------------------------------------------
__global__ __launch_bounds__(256) void wprep_kernel(
    const float* __restrict__ Wq, const float* __restrict__ Wk,
    const float* __restrict__ Wv, unsigned short* __restrict__ WT)
{
    const int mat = blockIdx.y;
    const float* W = (mat == 0) ? Wq : ((mat == 1) ? Wk : Wv);
    const int base = blockIdx.x * 2048;
    for (int ii = threadIdx.x; ii < 2048; ii += 256) {
        const int i = base + ii;          // i = k*64 + n
        const int k = i >> 6, n = i & 63;
        WT[((size_t)mat * HH + n) * EE + k] = f2h(W[i]);
    }
}

// ---------------------------------------------------------------------------
// QKV projection via fp16 MFMA — ZERO LDS, zero barriers.
// A-frag: 8 fp32 from X (per-lane contiguous 32B) converted in-register.
// B-frag: 8 fp16 from pre-transposed WT (L2-resident, 64 KB per matrix).
// grid (NQ/64, 3), block 256 (4 independent waves; wave w owns rows w*16..).
// Q pre-scaled by 1/sqrt(H)=0.125. Q,K row-major fp16; V transposed [b][h][s].
// ---------------------------------------------------------------------------
__global__ __launch_bounds__(256) void qkv_proj_kernel(
    const float* __restrict__ Xq, const float* __restrict__ Xk, const float* __restrict__ Xv,
    const float* __restrict__ bq, const float* __restrict__ bk, const float* __restrict__ bv,
    const unsigned short* __restrict__ WT,
    unsigned short* __restrict__ Qf, unsigned short* __restrict__ Kf,
    unsigned short* __restrict__ Vt)
{
    const int mtx = blockIdx.y;
    const float* X    = (mtx == 0) ? Xq : ((mtx == 1) ? Xk : Xv);
    const float* bias = (mtx == 0) ? bq : ((mtx == 1) ? bk : bv);

    const int tid  = threadIdx.x;
    const int lane = tid & 63;
    const int w    = tid >> 6;
    const int l15  = lane & 15;
    const int lg   = lane >> 4;
    const int r0   = blockIdx.x * 64;
    const int row  = r0 + w * 16 + l15;          // A-frag row for this lane

    const float* Xr = &X[(size_t)row * EE];
    const unsigned short* Wm = &WT[(size_t)mtx * HH * EE];

    f32x4 acc[4] = {{0,0,0,0},{0,0,0,0},{0,0,0,0},{0,0,0,0}};

    #pragma unroll 4
    for (int kk = 0; kk < EE / 32; ++kk) {       // 16 chunks of K=32
        const int kb = kk * 32 + lg * 8;
        const float4 xa = *(const float4*)&Xr[kb];
        const float4 xb = *(const float4*)&Xr[kb + 4];
        s16x8 a;
        a[0] = (short)f2h(xa.x); a[1] = (short)f2h(xa.y);
        a[2] = (short)f2h(xa.z); a[3] = (short)f2h(xa.w);
        a[4] = (short)f2h(xb.x); a[5] = (short)f2h(xb.y);
        a[6] = (short)f2h(xb.z); a[7] = (short)f2h(xb.w);
        #pragma unroll
        for (int f = 0; f < 4; ++f) {
            const s16x8 b = *(const s16x8*)&Wm[(size_t)(f * 16 + l15) * EE + kb];
            acc[f] = mfma_f16(a, b, acc[f]);
        }
    }

    float bcol[4];
    #pragma unroll
    for (int f = 0; f < 4; ++f) bcol[f] = bias[f * 16 + l15];
    const float qs = (mtx == 0) ? 0.125f : 1.0f;   // fold 1/sqrt(H) into Q

    if (mtx < 2) {
        unsigned short* Out = (mtx == 0) ? Qf : Kf;
        #pragma unroll
        for (int f = 0; f < 4; ++f)
            #pragma unroll
            for (int r = 0; r < 4; ++r)
                Out[(size_t)(r0 + w * 16 + lg * 4 + r) * HH + f * 16 + l15] =
                    f2h((acc[f][r] + bcol[f]) * qs);
    } else {
        const int b  = r0 >> 12;
        const int s0 = (r0 & 4095) + w * 16 + lg * 4;
        #pragma unroll
        for (int f = 0; f < 4; ++f) {
            ushort4 pk;
            pk.x = f2h(acc[f][0] + bcol[f]);
            pk.y = f2h(acc[f][1] + bcol[f]);
            pk.z = f2h(acc[f][2] + bcol[f]);
            pk.w = f2h(acc[f][3] + bcol[f]);
            *(ushort4*)&Vt[((size_t)b * HH + f * 16 + l15) * SS + s0] = pk;
        }
    }
}

// ---------------------------------------------------------------------------
// Causal flash attention via fp16 MFMA — NO K/V LDS staging (K,V are 512 KB
// per batch in fp16: L2-resident; frags loaded directly from global in MFMA
// B-layout). No __syncthreads at all; waves independent. Only per-wave P
// relayout buffer in LDS (8.7 KB/block -> 8 waves/SIMD occupancy).
// Defer-max online softmax (THR=8). Split-K partials.
// grid (S/64, NSPLIT, B), block 256 = 4 waves; wave owns 16 queries.
// ---------------------------------------------------------------------------
__global__ __launch_bounds__(256) void attn_partial_kernel(
    const unsigned short* __restrict__ Qf, const unsigned short* __restrict__ Kf,
    const unsigned short* __restrict__ Vt, float* __restrict__ o_part,
    float* __restrict__ m_part, float* __restrict__ l_part)
{
    __shared__ unsigned short Pl[4 * 16 * 68];   // per-wave [q'][key]

    const int tid  = threadIdx.x;
    const int b    = blockIdx.z;
    const int cch  = blockIdx.y;
    const int qb0  = blockIdx.x * 64;
    const int lane = tid & 63;
    const int w    = tid >> 6;
    const int l15  = lane & 15;
    const int lg   = lane >> 4;
    const int qw0  = qb0 + w * 16;

    const size_t qrow = (size_t)(b * SS + qw0 + l15) * HH;
    const s16x8 qf0 = *(const s16x8*)&Qf[qrow + lg * 8];
    const s16x8 qf1 = *(const s16x8*)&Qf[qrow + 32 + lg * 8];

    f32x4 o[4] = {{0,0,0,0},{0,0,0,0},{0,0,0,0},{0,0,0,0}};
    float m[4], l[4];
    #pragma unroll
    for (int r = 0; r < 4; ++r) { m[r] = -1.0e30f; l[r] = 0.f; }

    const unsigned short* Kb = Kf + (size_t)b * SS * HH;
    const unsigned short* Vb = Vt + (size_t)b * HH * SS;

    const int T   = blockIdx.x + 1;              // 64-key tiles needed
    const int tpc = (T + NSPLIT - 1) / NSPLIT;
    const int t0  = cch * tpc;
    const int t1  = min(t0 + tpc, T);
    unsigned short* PW = Pl + w * (16 * 68);

    for (int t = t0; t < t1; ++t) {
        const int k0 = t * 64;

        // QK^T (Q pre-scaled): B-frags straight from L2-resident K
        f32x4 sc[4];
        #pragma unroll
        for (int f = 0; f < 4; ++f) {
            const unsigned short* kr = &Kb[(size_t)(k0 + f * 16 + l15) * HH + lg * 8];
            const s16x8 kfa = *(const s16x8*)kr;
            const s16x8 kfb = *(const s16x8*)(kr + 32);
            f32x4 z = {0, 0, 0, 0};
            z = mfma_f16(qf0, kfa, z);
            z = mfma_f16(qf1, kfb, z);
            sc[f] = z;
        }

        float sv[4][4];
        #pragma unroll
        for (int f = 0; f < 4; ++f)
            #pragma unroll
            for (int r = 0; r < 4; ++r) sv[f][r] = sc[f][r];
        if (k0 + 63 > qw0) {            // diagonal tiles only (wave-uniform)
            #pragma unroll
            for (int f = 0; f < 4; ++f)
                #pragma unroll
                for (int r = 0; r < 4; ++r) {
                    const int qr = qw0 + lg * 4 + r;
                    if (k0 + f * 16 + l15 > qr) sv[f][r] = -3.0e38f;
                }
        }

        float tm[4];
        #pragma unroll
        for (int r = 0; r < 4; ++r)
            tm[r] = fmaxf(fmaxf(sv[0][r], sv[1][r]), fmaxf(sv[2][r], sv[3][r]));
        #pragma unroll
        for (int d = 1; d < 16; d <<= 1)
            #pragma unroll
            for (int r = 0; r < 4; ++r) tm[r] = fmaxf(tm[r], __shfl_xor(tm[r], d));

        // defer-max: rescale only when tile max grew past m+8
        bool grow = false;
        #pragma unroll
        for (int r = 0; r < 4; ++r) grow = grow || (tm[r] > m[r] + 8.0f);
        if (__any((int)grow)) {
            #pragma unroll
            for (int r = 0; r < 4; ++r) {
                const float mn = fmaxf(m[r], tm[r]);
                const float al = __expf(m[r] - mn);   // first tile: 0
                m[r] = mn;
                l[r] *= al;
                #pragma unroll
                for (int f = 0; f < 4; ++f) o[f][r] *= al;
            }
        }

        float p[4][4];
        #pragma unroll
        for (int f = 0; f < 4; ++f)
            #pragma unroll
            for (int r = 0; r < 4; ++r) p[f][r] = __expf(sv[f][r] - m[r]);
        #pragma unroll
        for (int r = 0; r < 4; ++r)
            l[r] += p[0][r] + p[1][r] + p[2][r] + p[3][r];

        // P relayout: C-layout (q=lg*4+r, key=f*16+l15) -> A-frag rows.
        // Per-wave buffer: no barrier needed (compiler orders via lgkmcnt).
        #pragma unroll
        for (int f = 0; f < 4; ++f)
            #pragma unroll
            for (int r = 0; r < 4; ++r)
                PW[(lg * 4 + r) * 68 + f * 16 + l15] = f2h(p[f][r]);
        const s16x8 pa0 = *(const s16x8*)&PW[l15 * 68 + lg * 8];
        const s16x8 pa1 = *(const s16x8*)&PW[l15 * 68 + 32 + lg * 8];

        // PV: B-frags straight from L2-resident V^T
        #pragma unroll
        for (int f = 0; f < 4; ++f) {
            const unsigned short* vr = &Vb[(size_t)(f * 16 + l15) * SS + k0 + lg * 8];
            const s16x8 vfa = *(const s16x8*)vr;
            const s16x8 vfb = *(const s16x8*)(vr + 32);
            o[f] = mfma_f16(pa0, vfa, o[f]);
            o[f] = mfma_f16(pa1, vfb, o[f]);
        }
    }

    #pragma unroll
    for (int d = 1; d < 16; d <<= 1)
        #pragma unroll
        for (int r = 0; r < 4; ++r) l[r] += __shfl_xor(l[r], d);

    #pragma unroll
    for (int r = 0; r < 4; ++r) {
        const size_t qlin = (size_t)b * SS + qb0 + w * 16 + lg * 4 + r;
        float* Op = o_part + ((size_t)cch * NQ + qlin) * HH;
        #pragma unroll
        for (int f = 0; f < 4; ++f) Op[f * 16 + l15] = o[f][r];
        if (l15 == 0) {
            m_part[(size_t)cch * NQ + qlin] = m[r];
            l_part[(size_t)cch * NQ + qlin] = l[r];
        }
    }
}

// ---------------------------------------------------------------------------
// Combine NSPLIT partials per query. One thread per (q, 4 h's).
// ---------------------------------------------------------------------------
__global__ __launch_bounds__(256) void attn_combine_kernel(
    const float* __restrict__ o_part, const float* __restrict__ m_part,
    const float* __restrict__ l_part, float* __restrict__ O)
{
    const int g = blockIdx.x * 256 + threadIdx.x;
    const size_t qlin = (size_t)(g >> 4);
    const int h0 = (g & 15) * 4;

    float mv[NSPLIT], lv[NSPLIT];
    float M = -INFINITY;
    #pragma unroll
    for (int cc = 0; cc < NSPLIT; ++cc) {
        mv[cc] = m_part[(size_t)cc * NQ + qlin];
        lv[cc] = l_part[(size_t)cc * NQ + qlin];
        M = fmaxf(M, mv[cc]);
    }
    float L = 0.f;
    float4 acc = make_float4(0.f, 0.f, 0.f, 0.f);
    #pragma unroll
    for (int cc = 0; cc < NSPLIT; ++cc) {
        const float wc = __expf(mv[cc] - M);
        L += lv[cc] * wc;
        const float4 oc = *(const float4*)&o_part[((size_t)cc * NQ + qlin) * HH + h0];
        acc.x += wc * oc.x; acc.y += wc * oc.y;
        acc.z += wc * oc.z; acc.w += wc * oc.w;
    }
    const float inv = 1.0f / L;
    acc.x *= inv; acc.y *= inv; acc.z *= inv; acc.w *= inv;
    *(float4*)&O[qlin * HH + h0] = acc;
}

// ---------------------------------------------------------------------------
extern "C" void kernel_launch(void* const* d_in, const int* in_sizes, int n_in,
                              void* d_out, int out_size, void* d_ws, size_t ws_size,
                              hipStream_t stream) {
    const float* xq = (const float*)d_in[0];
    const float* xk = (const float*)d_in[1];
    const float* xv = (const float*)d_in[2];
    const float* Wq = (const float*)d_in[3];
    const float* bq = (const float*)d_in[4];
    const float* Wk = (const float*)d_in[5];
    const float* bk = (const float*)d_in[6];
    const float* Wv = (const float*)d_in[7];
    const float* bv = (const float*)d_in[8];
    // d_in[9]: causal mask — deterministic, never read.

    unsigned short* Qf = (unsigned short*)d_ws;                  // 2 MiB
    unsigned short* Kf = Qf + (size_t)NQ * HH;                   // 2 MiB
    unsigned short* Vt = Kf + (size_t)NQ * HH;                   // 2 MiB
    unsigned short* WT = Vt + (size_t)NQ * HH;                   // 192 KiB
    float* o_part = (float*)(WT + (size_t)3 * HH * EE);          // 32 MiB
    float* m_part = o_part + (size_t)NSPLIT * NQ * HH;
    float* l_part = m_part + (size_t)NSPLIT * NQ;

    wprep_kernel<<<dim3(16, 3), 256, 0, stream>>>(Wq, Wk, Wv, WT);

    qkv_proj_kernel<<<dim3(NQ / 64, 3), 256, 0, stream>>>(
        xq, xk, xv, bq, bk, bv, WT, Qf, Kf, Vt);

    attn_partial_kernel<<<dim3(SS / 64, NSPLIT, BB), 256, 0, stream>>>(
        Qf, Kf, Vt, o_part, m_part, l_part);

    attn_combine_kernel<<<(NQ * 16) / 256, 256, 0, stream>>>(
        o_part, m_part, l_part, (float*)d_out);
}

// Round 9
// 446.495 us; speedup vs baseline: 1.1086x; 1.1086x over previous
//
#include <hip/hip_runtime.h>
#include <math.h>

#define BB 4
#define SS 4096
#define EE 512
#define HH 64
#define NSPLIT 4
#define NQ (BB * SS)          // 16384 rows

typedef _Float16 f16x8 __attribute__((ext_vector_type(8)));
typedef short    s16x8 __attribute__((ext_vector_type(8)));
typedef float    f32x4 __attribute__((ext_vector_type(4)));

static __device__ __forceinline__ unsigned short f2h(float f) {
    _Float16 h = (_Float16)f;
    return __builtin_bit_cast(unsigned short, h);
}

static __device__ __forceinline__ f32x4 mfma_f16(s16x8 a, s16x8 b, f32x4 c) {
    return __builtin_amdgcn_mfma_f32_16x16x32_f16(
        __builtin_bit_cast(f16x8, a), __builtin_bit_cast(f16x8, b), c, 0, 0, 0);
}

// ---------------------------------------------------------------------------
// W prep: fp32 W[512][64] -> transposed fp16 WT [mat][n=64][k=512].
// ---------------------------------------------------------------------------
__global__ __launch_bounds__(256) void wprep_kernel(
    const float* __restrict__ Wq, const float* __restrict__ Wk,
    const float* __restrict__ Wv, unsigned short* __restrict__ WT)
{
    const int mat = blockIdx.y;
    const float* W = (mat == 0) ? Wq : ((mat == 1) ? Wk : Wv);
    const int base = blockIdx.x * 2048;
    for (int ii = threadIdx.x; ii < 2048; ii += 256) {
        const int i = base + ii;          // i = k*64 + n
        const int k = i >> 6, n = i & 63;
        WT[((size_t)mat * HH + n) * EE + k] = f2h(W[i]);
    }
}

// ---------------------------------------------------------------------------
// QKV projection via fp16 MFMA (r6-proven LDS-staged version).
// grid (NQ/64, 3), block 256 (4 waves). 64x64 tile; K streamed in 8 chunks
// of 64; 8 MFMA per wave per chunk. Q pre-scaled by log2(e)/sqrt(H) so the
// attention softmax runs in exp2 domain. Q,K row-major fp16; V transposed.
// ---------------------------------------------------------------------------
__global__ __launch_bounds__(256) void qkv_proj_kernel(
    const float* __restrict__ Xq, const float* __restrict__ Xk, const float* __restrict__ Xv,
    const float* __restrict__ bq, const float* __restrict__ bk, const float* __restrict__ bv,
    const unsigned short* __restrict__ WT,
    unsigned short* __restrict__ Qf, unsigned short* __restrict__ Kf,
    unsigned short* __restrict__ Vt)
{
    const int mtx = blockIdx.y;
    const float* X    = (mtx == 0) ? Xq : ((mtx == 1) ? Xk : Xv);
    const float* bias = (mtx == 0) ? bq : ((mtx == 1) ? bk : bv);

    __shared__ unsigned short As[64 * 72];   // [row][k] fp16, stride 72
    __shared__ unsigned short Bs[64 * 72];   // [n][k] fp16 (pre-transposed W)

    const int tid  = threadIdx.x;
    const int lane = tid & 63;
    const int w    = tid >> 6;
    const int l15  = lane & 15;
    const int lg   = lane >> 4;
    const int r0   = blockIdx.x * 64;

    const int arow = tid >> 2;       // 0..63
    const int asg  = tid & 3;        // 0..3 (16 k-elems each)

    f32x4 acc[4] = {{0,0,0,0},{0,0,0,0},{0,0,0,0},{0,0,0,0}};

    for (int c = 0; c < EE / 64; ++c) {
        const float* xp = &X[(size_t)(r0 + arow) * EE + c * 64 + asg * 16];
        const float4 x0 = ((const float4*)xp)[0];
        const float4 x1 = ((const float4*)xp)[1];
        const float4 x2 = ((const float4*)xp)[2];
        const float4 x3 = ((const float4*)xp)[3];
        const size_t wb = ((size_t)mtx * HH + arow) * EE + c * 64 + asg * 16;
        const s16x8 w0 = *(const s16x8*)&WT[wb];
        const s16x8 w1 = *(const s16x8*)&WT[wb + 8];
        __syncthreads();   // previous chunk fully consumed

        const float xs[16] = {x0.x,x0.y,x0.z,x0.w, x1.x,x1.y,x1.z,x1.w,
                              x2.x,x2.y,x2.z,x2.w, x3.x,x3.y,x3.z,x3.w};
        s16x8 a0, a1;
        #pragma unroll
        for (int i = 0; i < 8; ++i) {
            a0[i] = (short)f2h(xs[i]);
            a1[i] = (short)f2h(xs[8 + i]);
        }
        *(s16x8*)&As[arow * 72 + asg * 16]     = a0;
        *(s16x8*)&As[arow * 72 + asg * 16 + 8] = a1;
        *(s16x8*)&Bs[arow * 72 + asg * 16]     = w0;
        *(s16x8*)&Bs[arow * 72 + asg * 16 + 8] = w1;
        __syncthreads();

        const int ma = (w * 16 + l15) * 72;
        const s16x8 af0 = *(const s16x8*)&As[ma + lg * 8];
        const s16x8 af1 = *(const s16x8*)&As[ma + 32 + lg * 8];
        #pragma unroll
        for (int f = 0; f < 4; ++f) {
            const int nb = (f * 16 + l15) * 72;
            const s16x8 bf0 = *(const s16x8*)&Bs[nb + lg * 8];
            const s16x8 bf1 = *(const s16x8*)&Bs[nb + 32 + lg * 8];
            acc[f] = mfma_f16(af0, bf0, acc[f]);
            acc[f] = mfma_f16(af1, bf1, acc[f]);
        }
    }

    float bcol[4];
    #pragma unroll
    for (int f = 0; f < 4; ++f) bcol[f] = bias[f * 16 + l15];
    // Q scale: (1/sqrt(64)) * log2(e)  -> softmax uses exp2 directly
    const float qs = (mtx == 0) ? 0.18033688f : 1.0f;

    if (mtx < 2) {
        unsigned short* Out = (mtx == 0) ? Qf : Kf;
        #pragma unroll
        for (int f = 0; f < 4; ++f)
            #pragma unroll
            for (int r = 0; r < 4; ++r)
                Out[(size_t)(r0 + w * 16 + lg * 4 + r) * HH + f * 16 + l15] =
                    f2h((acc[f][r] + bcol[f]) * qs);
    } else {
        const int b  = r0 >> 12;
        const int s0 = (r0 & 4095) + w * 16 + lg * 4;
        #pragma unroll
        for (int f = 0; f < 4; ++f) {
            ushort4 pk;
            pk.x = f2h(acc[f][0] + bcol[f]);
            pk.y = f2h(acc[f][1] + bcol[f]);
            pk.z = f2h(acc[f][2] + bcol[f]);
            pk.w = f2h(acc[f][3] + bcol[f]);
            *(ushort4*)&Vt[((size_t)b * HH + f * 16 + l15) * SS + s0] = pk;
        }
    }
}

// ---------------------------------------------------------------------------
// Causal flash attention via fp16 MFMA, KVBLK=64, single-buffer LDS with
// register prefetch (load next tile's regs before computing current tile).
// exp2-domain softmax (Q pre-scaled by log2e/8), defer-max (THR=8 nats =
// 11.54 log2-units). Split-K partials, NSPLIT=4.
// grid (S/64, NSPLIT, B), block 256 = 4 waves; wave owns 16 queries.
// ---------------------------------------------------------------------------
__global__ __launch_bounds__(256) void attn_partial_kernel(
    const unsigned short* __restrict__ Qf, const unsigned short* __restrict__ Kf,
    const unsigned short* __restrict__ Vt, float* __restrict__ o_part,
    float* __restrict__ m_part, float* __restrict__ l_part)
{
    __shared__ unsigned short Ks[64 * 68];       // [key][k]
    __shared__ unsigned short Vs[64 * 68];       // [h][key]
    __shared__ unsigned short Pl[4 * 16 * 68];   // per-wave [q'][key]

    const int tid  = threadIdx.x;
    const int b    = blockIdx.z;
    const int cch  = blockIdx.y;
    const int qb0  = blockIdx.x * 64;
    const int lane = tid & 63;
    const int w    = tid >> 6;
    const int l15  = lane & 15;
    const int lg   = lane >> 4;
    const int qw0  = qb0 + w * 16;

    const size_t qrow = (size_t)(b * SS + qw0 + l15) * HH;
    const s16x8 qf0 = *(const s16x8*)&Qf[qrow + lg * 8];
    const s16x8 qf1 = *(const s16x8*)&Qf[qrow + 32 + lg * 8];

    f32x4 o[4] = {{0,0,0,0},{0,0,0,0},{0,0,0,0},{0,0,0,0}};
    float m[4], l[4];
    #pragma unroll
    for (int r = 0; r < 4; ++r) { m[r] = -1.0e30f; l[r] = 0.f; }

    const int kkey = tid >> 2, ksg = tid & 3;
    const unsigned short* Kb = Kf + (size_t)b * SS * HH;
    const unsigned short* Vb = Vt + (size_t)b * HH * SS;

    const int T   = blockIdx.x + 1;              // 64-key tiles needed
    const int tpc = (T + NSPLIT - 1) / NSPLIT;
    const int t0  = cch * tpc;
    const int t1  = min(t0 + tpc, T);
    const int nt  = t1 - t0;
    unsigned short* PW = Pl + w * (16 * 68);

    s16x8 ka, kb2, va, vb2;

    if (nt > 0) {
        const int k0 = t0 * 64;
        ka  = *(const s16x8*)&Kb[(size_t)(k0 + kkey) * HH + ksg * 8];
        kb2 = *(const s16x8*)&Kb[(size_t)(k0 + kkey) * HH + 32 + ksg * 8];
        va  = *(const s16x8*)&Vb[(size_t)kkey * SS + k0 + ksg * 8];
        vb2 = *(const s16x8*)&Vb[(size_t)kkey * SS + k0 + 32 + ksg * 8];
        *(s16x8*)&Ks[kkey * 68 + ksg * 8]      = ka;
        *(s16x8*)&Ks[kkey * 68 + 32 + ksg * 8] = kb2;
        *(s16x8*)&Vs[kkey * 68 + ksg * 8]      = va;
        *(s16x8*)&Vs[kkey * 68 + 32 + ksg * 8] = vb2;
        __syncthreads();
    }

    for (int i = 0; i < nt; ++i) {
        const int t  = t0 + i;
        const int k0 = t * 64;

        if (i + 1 < nt) {                        // prefetch next tile to regs
            const int kn = (t + 1) * 64;
            ka  = *(const s16x8*)&Kb[(size_t)(kn + kkey) * HH + ksg * 8];
            kb2 = *(const s16x8*)&Kb[(size_t)(kn + kkey) * HH + 32 + ksg * 8];
            va  = *(const s16x8*)&Vb[(size_t)kkey * SS + kn + ksg * 8];
            vb2 = *(const s16x8*)&Vb[(size_t)kkey * SS + kn + 32 + ksg * 8];
        }

        // QK^T (Q pre-scaled into exp2 domain)
        f32x4 sc[4];
        #pragma unroll
        for (int f = 0; f < 4; ++f) {
            const int kr = (f * 16 + l15) * 68;
            const s16x8 kfa = *(const s16x8*)&Ks[kr + lg * 8];
            const s16x8 kfb = *(const s16x8*)&Ks[kr + 32 + lg * 8];
            f32x4 z = {0, 0, 0, 0};
            z = mfma_f16(qf0, kfa, z);
            z = mfma_f16(qf1, kfb, z);
            sc[f] = z;
        }

        float sv[4][4];
        #pragma unroll
        for (int f = 0; f < 4; ++f)
            #pragma unroll
            for (int r = 0; r < 4; ++r) sv[f][r] = sc[f][r];
        if (k0 + 63 > qw0) {            // diagonal tiles only (wave-uniform)
            #pragma unroll
            for (int f = 0; f < 4; ++f)
                #pragma unroll
                for (int r = 0; r < 4; ++r) {
                    const int qr = qw0 + lg * 4 + r;
                    if (k0 + f * 16 + l15 > qr) sv[f][r] = -3.0e38f;
                }
        }

        float tm[4];
        #pragma unroll
        for (int r = 0; r < 4; ++r)
            tm[r] = fmaxf(fmaxf(sv[0][r], sv[1][r]), fmaxf(sv[2][r], sv[3][r]));
        #pragma unroll
        for (int d = 1; d < 16; d <<= 1)
            #pragma unroll
            for (int r = 0; r < 4; ++r) tm[r] = fmaxf(tm[r], __shfl_xor(tm[r], d));

        // defer-max: rescale only when tile max grew past m + 8 nats
        bool grow = false;
        #pragma unroll
        for (int r = 0; r < 4; ++r) grow = grow || (tm[r] > m[r] + 11.5416f);
        if (__any((int)grow)) {
            #pragma unroll
            for (int r = 0; r < 4; ++r) {
                const float mn = fmaxf(m[r], tm[r]);
                const float al = exp2f(m[r] - mn);   // first tile: 0
                m[r] = mn;
                l[r] *= al;
                #pragma unroll
                for (int f = 0; f < 4; ++f) o[f][r] *= al;
            }
        }

        float p[4][4];
        #pragma unroll
        for (int f = 0; f < 4; ++f)
            #pragma unroll
            for (int r = 0; r < 4; ++r) p[f][r] = exp2f(sv[f][r] - m[r]);
        #pragma unroll
        for (int r = 0; r < 4; ++r)
            l[r] += p[0][r] + p[1][r] + p[2][r] + p[3][r];

        // P relayout: C-layout (q=lg*4+r, key=f*16+l15) -> A-frag rows.
        // Per-wave buffer; intra-wave LDS ordering via lgkmcnt (r7-proven).
        #pragma unroll
        for (int f = 0; f < 4; ++f)
            #pragma unroll
            for (int r = 0; r < 4; ++r)
                PW[(lg * 4 + r) * 68 + f * 16 + l15] = f2h(p[f][r]);
        const s16x8 pa0 = *(const s16x8*)&PW[l15 * 68 + lg * 8];
        const s16x8 pa1 = *(const s16x8*)&PW[l15 * 68 + 32 + lg * 8];

        #pragma unroll
        for (int f = 0; f < 4; ++f) {
            const int vr = (f * 16 + l15) * 68;
            const s16x8 vfa = *(const s16x8*)&Vs[vr + lg * 8];
            const s16x8 vfb = *(const s16x8*)&Vs[vr + 32 + lg * 8];
            o[f] = mfma_f16(pa0, vfa, o[f]);
            o[f] = mfma_f16(pa1, vfb, o[f]);
        }

        if (i + 1 < nt) {                        // publish prefetched tile
            __syncthreads();                     // all waves done reading
            *(s16x8*)&Ks[kkey * 68 + ksg * 8]      = ka;
            *(s16x8*)&Ks[kkey * 68 + 32 + ksg * 8] = kb2;
            *(s16x8*)&Vs[kkey * 68 + ksg * 8]      = va;
            *(s16x8*)&Vs[kkey * 68 + 32 + ksg * 8] = vb2;
            __syncthreads();                     // new tile visible
        }
    }

    #pragma unroll
    for (int d = 1; d < 16; d <<= 1)
        #pragma unroll
        for (int r = 0; r < 4; ++r) l[r] += __shfl_xor(l[r], d);

    #pragma unroll
    for (int r = 0; r < 4; ++r) {
        const size_t qlin = (size_t)b * SS + qb0 + w * 16 + lg * 4 + r;
        float* Op = o_part + ((size_t)cch * NQ + qlin) * HH;
        #pragma unroll
        for (int f = 0; f < 4; ++f) Op[f * 16 + l15] = o[f][r];
        if (l15 == 0) {
            m_part[(size_t)cch * NQ + qlin] = m[r];
            l_part[(size_t)cch * NQ + qlin] = l[r];
        }
    }
}

// ---------------------------------------------------------------------------
// Combine NSPLIT partials per query (exp2 domain). One thread per (q, 4 h).
// ---------------------------------------------------------------------------
__global__ __launch_bounds__(256) void attn_combine_kernel(
    const float* __restrict__ o_part, const float* __restrict__ m_part,
    const float* __restrict__ l_part, float* __restrict__ O)
{
    const int g = blockIdx.x * 256 + threadIdx.x;
    const size_t qlin = (size_t)(g >> 4);
    const int h0 = (g & 15) * 4;

    float mv[NSPLIT], lv[NSPLIT];
    float M = -INFINITY;
    #pragma unroll
    for (int cc = 0; cc < NSPLIT; ++cc) {
        mv[cc] = m_part[(size_t)cc * NQ + qlin];
        lv[cc] = l_part[(size_t)cc * NQ + qlin];
        M = fmaxf(M, mv[cc]);
    }
    float L = 0.f;
    float4 acc = make_float4(0.f, 0.f, 0.f, 0.f);
    #pragma unroll
    for (int cc = 0; cc < NSPLIT; ++cc) {
        const float wc = exp2f(mv[cc] - M);
        L += lv[cc] * wc;
        const float4 oc = *(const float4*)&o_part[((size_t)cc * NQ + qlin) * HH + h0];
        acc.x += wc * oc.x; acc.y += wc * oc.y;
        acc.z += wc * oc.z; acc.w += wc * oc.w;
    }
    const float inv = 1.0f / L;
    acc.x *= inv; acc.y *= inv; acc.z *= inv; acc.w *= inv;
    *(float4*)&O[qlin * HH + h0] = acc;
}

// ---------------------------------------------------------------------------
extern "C" void kernel_launch(void* const* d_in, const int* in_sizes, int n_in,
                              void* d_out, int out_size, void* d_ws, size_t ws_size,
                              hipStream_t stream) {
    const float* xq = (const float*)d_in[0];
    const float* xk = (const float*)d_in[1];
    const float* xv = (const float*)d_in[2];
    const float* Wq = (const float*)d_in[3];
    const float* bq = (const float*)d_in[4];
    const float* Wk = (const float*)d_in[5];
    const float* bk = (const float*)d_in[6];
    const float* Wv = (const float*)d_in[7];
    const float* bv = (const float*)d_in[8];
    // d_in[9]: causal mask — deterministic, never read.

    unsigned short* Qf = (unsigned short*)d_ws;                  // 2 MiB
    unsigned short* Kf = Qf + (size_t)NQ * HH;                   // 2 MiB
    unsigned short* Vt = Kf + (size_t)NQ * HH;                   // 2 MiB
    unsigned short* WT = Vt + (size_t)NQ * HH;                   // 192 KiB
    float* o_part = (float*)(WT + (size_t)3 * HH * EE);          // 16 MiB
    float* m_part = o_part + (size_t)NSPLIT * NQ * HH;
    float* l_part = m_part + (size_t)NSPLIT * NQ;

    wprep_kernel<<<dim3(16, 3), 256, 0, stream>>>(Wq, Wk, Wv, WT);

    qkv_proj_kernel<<<dim3(NQ / 64, 3), 256, 0, stream>>>(
        xq, xk, xv, bq, bk, bv, WT, Qf, Kf, Vt);

    attn_partial_kernel<<<dim3(SS / 64, NSPLIT, BB), 256, 0, stream>>>(
        Qf, Kf, Vt, o_part, m_part, l_part);

    attn_combine_kernel<<<(NQ * 16) / 256, 256, 0, stream>>>(
        o_part, m_part, l_part, (float*)d_out);
}